// Round 19
// baseline (479.145 us; speedup 1.0000x reference)
//
#include <hip/hip_runtime.h>
#include <hip/hip_bf16.h>
#include <cstdint>

// ---------------------------------------------------------------------------
// GAT 3-layer forward. N=50000, E=800000, H=4, D=64 (FEAT = H*D = 256 = F_IN).
// R19: (1) GEMM k-loop: A/B global loads moved AFTER the barrier with a
//      register double-buffer for B (hipcc drains vmcnt(0) before s_barrier,
//      so loads issued pre-barrier serialize their full L2 latency every iter);
//      (2) agg gather: unrolled cnt==16 fast path (runtime trip count blocked
//      unrolling -> one gather in flight; now 8 batched).
// ---------------------------------------------------------------------------

#define FEAT 256
#define NHEAD 4

typedef short short8 __attribute__((ext_vector_type(8)));
typedef float f32x4 __attribute__((ext_vector_type(4)));

__device__ __forceinline__ ushort f2bf(float v) {
    uint u = __float_as_uint(v);
    uint r = (u + 0x7fffu + ((u >> 16) & 1u)) >> 16;
    return (ushort)r;
}
__device__ __forceinline__ float bf2f(ushort h) {
    return __uint_as_float(((uint)h) << 16);
}

// ---------------- CSR build ----------------
__global__ void hist_kernel(const int* __restrict__ dst, int* __restrict__ deg, int E) {
    int e = blockIdx.x * 256 + threadIdx.x;
    if (e < E) atomicAdd(&deg[dst[e]], 1);
}

__global__ void scan_block(const int* __restrict__ deg, int* __restrict__ offs,
                           int* __restrict__ bsums, int n) {
    __shared__ int s[256];
    int i = blockIdx.x * 256 + threadIdx.x;
    int v = (i < n) ? deg[i] : 0;
    s[threadIdx.x] = v; __syncthreads();
    #pragma unroll
    for (int off = 1; off < 256; off <<= 1) {
        int t = (threadIdx.x >= off) ? s[threadIdx.x - off] : 0;
        __syncthreads();
        s[threadIdx.x] += t;
        __syncthreads();
    }
    if (i < n) offs[i] = s[threadIdx.x] - v;
    if (threadIdx.x == 255) bsums[blockIdx.x] = s[255];
}

__global__ void scan_sums(int* __restrict__ bsums, int nb) {
    __shared__ int s[256];
    int v = (threadIdx.x < nb) ? bsums[threadIdx.x] : 0;
    s[threadIdx.x] = v; __syncthreads();
    #pragma unroll
    for (int off = 1; off < 256; off <<= 1) {
        int t = (threadIdx.x >= off) ? s[threadIdx.x - off] : 0;
        __syncthreads();
        s[threadIdx.x] += t;
        __syncthreads();
    }
    if (threadIdx.x < nb) bsums[threadIdx.x] = s[threadIdx.x] - v;
}

__global__ void scan_add(int* __restrict__ offs, int* __restrict__ cursor,
                         const int* __restrict__ bsums, int n, int total) {
    int i = blockIdx.x * 256 + threadIdx.x;
    if (i < n) {
        int o = offs[i] + bsums[i >> 8];
        offs[i] = o;
        cursor[i] = o;
    }
    if (i == 0) offs[n] = total;
}

__global__ void scatter_kernel(const int* __restrict__ src, const int* __restrict__ dst,
                               int* __restrict__ cursor, int* __restrict__ csr_src, int E) {
    int e = blockIdx.x * 256 + threadIdx.x;
    if (e < E) {
        int d = dst[e];
        int pos = atomicAdd(&cursor[d], 1);
        csr_src[pos] = src[e];
    }
}

// ---------------- W prep (all 3 layers in one dispatch) ----------------
__global__ void wprep3_kernel(const float* __restrict__ W0, const float* __restrict__ W1,
                              const float* __restrict__ W2,
                              ushort* __restrict__ Wh0, ushort* __restrict__ Wl0,
                              ushort* __restrict__ Wh1, ushort* __restrict__ Wl1,
                              ushort* __restrict__ Wh2, ushort* __restrict__ Wl2) {
    const float* W = (blockIdx.y == 0) ? W0 : (blockIdx.y == 1) ? W1 : W2;
    ushort* Wh = (blockIdx.y == 0) ? Wh0 : (blockIdx.y == 1) ? Wh1 : Wh2;
    ushort* Wl = (blockIdx.y == 0) ? Wl0 : (blockIdx.y == 1) ? Wl1 : Wl2;
    int n = blockIdx.x;
    int k = threadIdx.x;
    float v = W[(size_t)k * FEAT + n];
    ushort h = f2bf(v);
    float r = v - bf2f(h);
    Wh[(size_t)n * FEAT + k] = h;
    Wl[(size_t)n * FEAT + k] = f2bf(r);
}

// ---------------- fused GEMM 64x256 ----------------
#define GBM 64
#define GBK 32
#define LDK 40    // padded K stride in ushorts (80 B rows)
#define NKIT (FEAT / GBK)   // 8
#define TLD 264   // epilogue transpose row stride (ushorts)
#define SMEM_USHORTS 16896  // max(k-loop 10240, epilogue 64*264)

__device__ __forceinline__ void gemm_epilogue(ushort* smem, f32x4 (*acc)[4],
                                              const float* alv, const float* arv,
                                              ushort* featB, float* el, float* er,
                                              int row0, int wid, int lane, int tid, int M) {
    const int fr = lane & 15;
    const int q  = lane >> 4;
    float al4[4], ar4[4];
    #pragma unroll
    for (int nt = 0; nt < 4; ++nt) {
        al4[nt] = alv[wid * 64 + nt * 16 + fr];
        ar4[nt] = arv[wid * 64 + nt * 16 + fr];
    }
    #pragma unroll
    for (int mt = 0; mt < 4; ++mt) {
        #pragma unroll
        for (int r = 0; r < 4; ++r) {
            int row = row0 + mt * 16 + q * 4 + r;
            bool ok = row < M;
            float pl = 0.f, pr = 0.f;
            #pragma unroll
            for (int nt = 0; nt < 4; ++nt) {
                float v = acc[mt][nt][r];
                pl = fmaf(v, al4[nt], pl);
                pr = fmaf(v, ar4[nt], pr);
            }
            #pragma unroll
            for (int o = 1; o < 16; o <<= 1) {
                pl += __shfl_xor(pl, o, 64);
                pr += __shfl_xor(pr, o, 64);
            }
            if (ok && fr == 0) {
                el[(size_t)row * NHEAD + wid] = pl;
                er[(size_t)row * NHEAD + wid] = pr;
            }
        }
    }
    __syncthreads();
    ushort (*T)[TLD] = (ushort(*)[TLD])smem;
    #pragma unroll
    for (int mt = 0; mt < 4; ++mt) {
        #pragma unroll
        for (int nt = 0; nt < 4; ++nt) {
            #pragma unroll
            for (int r = 0; r < 4; ++r) {
                int row = mt * 16 + q * 4 + r;
                T[row][wid * 64 + nt * 16 + fr] = f2bf(acc[mt][nt][r]);
            }
        }
    }
    __syncthreads();
    #pragma unroll
    for (int j = 0; j < 8; ++j) {
        int p = j * 256 + tid;
        int row = p >> 5;
        int pc = p & 31;
        if (row0 + row < M) {
            short8 v = *(const short8*)&T[row][pc * 8];
            *(short8*)(featB + (size_t)(row0 + row) * FEAT + pc * 8) = v;
        }
    }
}

__global__ __launch_bounds__(256) void gemm_fused(const ushort* __restrict__ Ahg,
                                                  const ushort* __restrict__ Alg,
                                                  const ushort* __restrict__ Whg,
                                                  const ushort* __restrict__ Wlg,
                                                  const float* __restrict__ alv,
                                                  const float* __restrict__ arv,
                                                  ushort* __restrict__ featB,
                                                  float* __restrict__ el,
                                                  float* __restrict__ er, int M) {
    __shared__ ushort smem[SMEM_USHORTS];
    ushort (*Ah)[GBM][LDK] = (ushort(*)[GBM][LDK])smem;
    ushort (*Al)[GBM][LDK] = (ushort(*)[GBM][LDK])(smem + 2 * GBM * LDK);

    const int tid  = threadIdx.x;
    const int lane = tid & 63;
    const int wid  = tid >> 6;
    const int row0 = blockIdx.x * GBM;

    const int arow = tid >> 2;
    const int achk = (tid & 3) * 8;
    const bool aok = (row0 + arow) < M;
    const ushort* ApH = Ahg + (size_t)(row0 + arow) * FEAT + achk;
    const ushort* ApL = Alg + (size_t)(row0 + arow) * FEAT + achk;

    const int fr = lane & 15;
    const int fk = (lane >> 4) * 8;

    f32x4 acc[4][4];
    #pragma unroll
    for (int i = 0; i < 4; ++i)
        #pragma unroll
        for (int j = 0; j < 4; ++j) {
            f32x4 z = {0.f, 0.f, 0.f, 0.f};
            acc[i][j] = z;
        }

    const short8 z8 = {0, 0, 0, 0, 0, 0, 0, 0};
    short8 bfh[2][4], bfl[2][4];

    // prologue: stage A(0) into LDS[0]; load B(0) into reg buf 0
    {
        short8 a_h = aok ? *(const short8*)(ApH) : z8;
        short8 a_l = aok ? *(const short8*)(ApL) : z8;
        *(short8*)&Ah[0][arow][achk] = a_h;
        *(short8*)&Al[0][arow][achk] = a_l;
        #pragma unroll
        for (int nt = 0; nt < 4; ++nt) {
            size_t boff = (size_t)(wid * 64 + nt * 16 + fr) * FEAT + fk;
            bfh[0][nt] = *(const short8*)(Whg + boff);
            bfl[0][nt] = *(const short8*)(Wlg + boff);
        }
    }

    #pragma unroll
    for (int t = 0; t < NKIT; ++t) {
        const int cur = t & 1;
        const int k1 = (t + 1) * GBK;
        __syncthreads();   // A(t) LDS visible; drains in-flight (needed now)
        // issue next-iter loads AFTER the barrier so MFMA(t) hides their latency
        short8 a_h = z8, a_l = z8;
        if (t + 1 < NKIT) {
            if (aok) {
                a_h = *(const short8*)(ApH + k1);
                a_l = *(const short8*)(ApL + k1);
            }
            #pragma unroll
            for (int nt = 0; nt < 4; ++nt) {
                size_t boff = (size_t)(wid * 64 + nt * 16 + fr) * FEAT + k1 + fk;
                bfh[cur ^ 1][nt] = *(const short8*)(Whg + boff);
                bfl[cur ^ 1][nt] = *(const short8*)(Wlg + boff);
            }
        }
        #pragma unroll
        for (int mt = 0; mt < 4; ++mt) {
            short8 afh = *(const short8*)&Ah[cur][mt * 16 + fr][fk];
            short8 afl = *(const short8*)&Al[cur][mt * 16 + fr][fk];
            #pragma unroll
            for (int nt = 0; nt < 4; ++nt) {
                acc[mt][nt] = __builtin_amdgcn_mfma_f32_16x16x32_bf16(
                    afh, bfh[cur][nt], acc[mt][nt], 0, 0, 0);
                acc[mt][nt] = __builtin_amdgcn_mfma_f32_16x16x32_bf16(
                    afh, bfl[cur][nt], acc[mt][nt], 0, 0, 0);
                acc[mt][nt] = __builtin_amdgcn_mfma_f32_16x16x32_bf16(
                    afl, bfh[cur][nt], acc[mt][nt], 0, 0, 0);
            }
        }
        if (t + 1 < NKIT) {
            *(short8*)&Ah[cur ^ 1][arow][achk] = a_h;   // waits A loads (post-MFMA)
            *(short8*)&Al[cur ^ 1][arow][achk] = a_l;
        }
    }

    gemm_epilogue(smem, acc, alv, arv, featB, el, er, row0, wid, lane, tid, M);
}

// ---------------- layer-1 GEMM: f32 A input, hi/lo split inline at staging ------
__global__ __launch_bounds__(256) void gemm_fused_f32a(const float* __restrict__ Af,
                                                       const ushort* __restrict__ Whg,
                                                       const ushort* __restrict__ Wlg,
                                                       const float* __restrict__ alv,
                                                       const float* __restrict__ arv,
                                                       ushort* __restrict__ featB,
                                                       float* __restrict__ el,
                                                       float* __restrict__ er, int M) {
    __shared__ ushort smem[SMEM_USHORTS];
    ushort (*Ah)[GBM][LDK] = (ushort(*)[GBM][LDK])smem;
    ushort (*Al)[GBM][LDK] = (ushort(*)[GBM][LDK])(smem + 2 * GBM * LDK);

    const int tid  = threadIdx.x;
    const int lane = tid & 63;
    const int wid  = tid >> 6;
    const int row0 = blockIdx.x * GBM;

    const int arow = tid >> 2;
    const int achk = (tid & 3) * 8;
    const bool aok = (row0 + arow) < M;
    const float* Ap = Af + (size_t)(row0 + arow) * FEAT + achk;

    const int fr = lane & 15;
    const int fk = (lane >> 4) * 8;

    f32x4 acc[4][4];
    #pragma unroll
    for (int i = 0; i < 4; ++i)
        #pragma unroll
        for (int j = 0; j < 4; ++j) {
            f32x4 z = {0.f, 0.f, 0.f, 0.f};
            acc[i][j] = z;
        }

    const float4 z4 = make_float4(0.f, 0.f, 0.f, 0.f);
    short8 bfh[2][4], bfl[2][4];

    auto split_store = [&](int buf, float4 f0, float4 f1) {
        float v[8] = {f0.x, f0.y, f0.z, f0.w, f1.x, f1.y, f1.z, f1.w};
        ushort hi[8], lo[8];
        #pragma unroll
        for (int k = 0; k < 8; ++k) {
            hi[k] = f2bf(v[k]);
            lo[k] = f2bf(v[k] - bf2f(hi[k]));
        }
        *(short8*)&Ah[buf][arow][achk] = *(short8*)hi;
        *(short8*)&Al[buf][arow][achk] = *(short8*)lo;
    };

    // prologue
    {
        float4 f0 = aok ? *(const float4*)(Ap)     : z4;
        float4 f1 = aok ? *(const float4*)(Ap + 4) : z4;
        split_store(0, f0, f1);
        #pragma unroll
        for (int nt = 0; nt < 4; ++nt) {
            size_t boff = (size_t)(wid * 64 + nt * 16 + fr) * FEAT + fk;
            bfh[0][nt] = *(const short8*)(Whg + boff);
            bfl[0][nt] = *(const short8*)(Wlg + boff);
        }
    }

    #pragma unroll
    for (int t = 0; t < NKIT; ++t) {
        const int cur = t & 1;
        const int k1 = (t + 1) * GBK;
        __syncthreads();
        float4 f0 = z4, f1 = z4;
        if (t + 1 < NKIT) {
            if (aok) {
                f0 = *(const float4*)(Ap + k1);
                f1 = *(const float4*)(Ap + k1 + 4);
            }
            #pragma unroll
            for (int nt = 0; nt < 4; ++nt) {
                size_t boff = (size_t)(wid * 64 + nt * 16 + fr) * FEAT + k1 + fk;
                bfh[cur ^ 1][nt] = *(const short8*)(Whg + boff);
                bfl[cur ^ 1][nt] = *(const short8*)(Wlg + boff);
            }
        }
        #pragma unroll
        for (int mt = 0; mt < 4; ++mt) {
            short8 afh = *(const short8*)&Ah[cur][mt * 16 + fr][fk];
            short8 afl = *(const short8*)&Al[cur][mt * 16 + fr][fk];
            #pragma unroll
            for (int nt = 0; nt < 4; ++nt) {
                acc[mt][nt] = __builtin_amdgcn_mfma_f32_16x16x32_bf16(
                    afh, bfh[cur][nt], acc[mt][nt], 0, 0, 0);
                acc[mt][nt] = __builtin_amdgcn_mfma_f32_16x16x32_bf16(
                    afh, bfl[cur][nt], acc[mt][nt], 0, 0, 0);
                acc[mt][nt] = __builtin_amdgcn_mfma_f32_16x16x32_bf16(
                    afl, bfh[cur][nt], acc[mt][nt], 0, 0, 0);
            }
        }
        if (t + 1 < NKIT) split_store(cur ^ 1, f0, f1);
    }

    gemm_epilogue(smem, acc, alv, arv, featB, el, er, row0, wid, lane, tid, M);
}

// ---------------- online-softmax aggregate, 2 edges per 16B load ----------------
__global__ __launch_bounds__(256) void agg_kernel5(const ushort* __restrict__ featB,
                                                   const float* __restrict__ el,
                                                   const float* __restrict__ er,
                                                   const int* __restrict__ offs,
                                                   const int* __restrict__ csr_src,
                                                   const float* __restrict__ bias,
                                                   float* __restrict__ outF,
                                                   ushort* __restrict__ outH,
                                                   ushort* __restrict__ outL,
                                                   int act, int n) {
    int node = blockIdx.x * 4 + (threadIdx.x >> 6);
    if (node >= n) return;
    int lane = threadIdx.x & 63;
    int h   = lane >> 4;
    int j16 = lane & 15;
    int l31 = lane & 31;
    int par = lane >> 5;
    int fb  = l31 * 8;
    int hh  = l31 >> 3;
    int start = offs[node];
    int deg = offs[node + 1] - start;
    float erh = er[node * NHEAD + h];

    float m = -1e30f, ssum = 0.f;
    float a0 = 0.f, a1 = 0.f, a2 = 0.f, a3 = 0.f;
    float a4 = 0.f, a5 = 0.f, a6 = 0.f, a7 = 0.f;
    int sidx = (j16 < deg) ? csr_src[start + j16] : 0;

    for (int p0 = 0; p0 < deg; p0 += 16) {
        int pn = p0 + 16 + j16;
        int sidx_nx = (pn < deg) ? csr_src[start + pn] : 0;
        float e = -1e30f;
        if (p0 + j16 < deg) {
            float t = el[sidx * NHEAD + h] + erh;
            e = (t > 0.f) ? t : 0.2f * t;
        }
        float cm = e;
        #pragma unroll
        for (int o = 1; o < 16; o <<= 1) cm = fmaxf(cm, __shfl_xor(cm, o, 64));
        float newm = fmaxf(m, cm);
        float sc = __expf(m - newm);
        m = newm;
        ssum *= sc;
        float w = __expf(e - m);
        ssum += w;
        float scA = __shfl(sc, hh * 16, 64);
        a0 *= scA; a1 *= scA; a2 *= scA; a3 *= scA;
        a4 *= scA; a5 *= scA; a6 *= scA; a7 *= scA;
        int cnt = min(16, deg - p0);
        if (cnt == 16) {
            #pragma unroll
            for (int i = 0; i < 8; ++i) {      // compile-time: 8 gathers in flight
                int j0 = 2 * i + par;
                int sj = __shfl(sidx, j0, 16);
                float wj = __shfl(w, hh * 16 + j0, 64);
                short8 v = *(const short8*)(featB + (size_t)sj * FEAT + fb);
                a0 = fmaf(wj, bf2f((ushort)v[0]), a0);
                a1 = fmaf(wj, bf2f((ushort)v[1]), a1);
                a2 = fmaf(wj, bf2f((ushort)v[2]), a2);
                a3 = fmaf(wj, bf2f((ushort)v[3]), a3);
                a4 = fmaf(wj, bf2f((ushort)v[4]), a4);
                a5 = fmaf(wj, bf2f((ushort)v[5]), a5);
                a6 = fmaf(wj, bf2f((ushort)v[6]), a6);
                a7 = fmaf(wj, bf2f((ushort)v[7]), a7);
            }
        } else {
            int iters = (cnt + 1) >> 1;
            for (int i = 0; i < iters; ++i) {
                int j0 = 2 * i + par;
                int sj = __shfl(sidx, j0, 16);
                float wj = __shfl(w, hh * 16 + j0, 64);
                short8 v = *(const short8*)(featB + (size_t)sj * FEAT + fb);
                a0 = fmaf(wj, bf2f((ushort)v[0]), a0);
                a1 = fmaf(wj, bf2f((ushort)v[1]), a1);
                a2 = fmaf(wj, bf2f((ushort)v[2]), a2);
                a3 = fmaf(wj, bf2f((ushort)v[3]), a3);
                a4 = fmaf(wj, bf2f((ushort)v[4]), a4);
                a5 = fmaf(wj, bf2f((ushort)v[5]), a5);
                a6 = fmaf(wj, bf2f((ushort)v[6]), a6);
                a7 = fmaf(wj, bf2f((ushort)v[7]), a7);
            }
        }
        sidx = sidx_nx;
    }
    a0 += __shfl_xor(a0, 32, 64);
    a1 += __shfl_xor(a1, 32, 64);
    a2 += __shfl_xor(a2, 32, 64);
    a3 += __shfl_xor(a3, 32, 64);
    a4 += __shfl_xor(a4, 32, 64);
    a5 += __shfl_xor(a5, 32, 64);
    a6 += __shfl_xor(a6, 32, 64);
    a7 += __shfl_xor(a7, 32, 64);

    float st = ssum;
    #pragma unroll
    for (int o = 1; o < 16; o <<= 1) st += __shfl_xor(st, o, 64);
    float stA = __shfl(st, hh * 16, 64);
    if (par == 0) {
        float inv = 1.f / fmaxf(stA, 1e-9f);
        float4 b0 = *(const float4*)(bias + fb);
        float4 b1 = *(const float4*)(bias + fb + 4);
        float o0 = fmaf(a0, inv, b0.x);
        float o1 = fmaf(a1, inv, b0.y);
        float o2 = fmaf(a2, inv, b0.z);
        float o3 = fmaf(a3, inv, b0.w);
        float o4 = fmaf(a4, inv, b1.x);
        float o5 = fmaf(a5, inv, b1.y);
        float o6 = fmaf(a6, inv, b1.z);
        float o7 = fmaf(a7, inv, b1.w);
        if (act) {
            o0 = (o0 > 0.f) ? o0 : expm1f(o0);
            o1 = (o1 > 0.f) ? o1 : expm1f(o1);
            o2 = (o2 > 0.f) ? o2 : expm1f(o2);
            o3 = (o3 > 0.f) ? o3 : expm1f(o3);
            o4 = (o4 > 0.f) ? o4 : expm1f(o4);
            o5 = (o5 > 0.f) ? o5 : expm1f(o5);
            o6 = (o6 > 0.f) ? o6 : expm1f(o6);
            o7 = (o7 > 0.f) ? o7 : expm1f(o7);
        }
        if (outF) {
            *((float4*)(outF + (size_t)node * FEAT + fb))     = make_float4(o0, o1, o2, o3);
            *((float4*)(outF + (size_t)node * FEAT + fb + 4)) = make_float4(o4, o5, o6, o7);
        } else {
            ushort hi[8], lo[8];
            float ov[8] = {o0, o1, o2, o3, o4, o5, o6, o7};
            #pragma unroll
            for (int k = 0; k < 8; ++k) {
                hi[k] = f2bf(ov[k]);
                lo[k] = f2bf(ov[k] - bf2f(hi[k]));
            }
            *(short8*)(outH + (size_t)node * FEAT + fb) = *(short8*)hi;
            *(short8*)(outL + (size_t)node * FEAT + fb) = *(short8*)lo;
        }
    }
}

// ---------------------------------------------------------------------------
extern "C" void kernel_launch(void* const* d_in, const int* in_sizes, int n_in,
                              void* d_out, int out_size, void* d_ws, size_t ws_size,
                              hipStream_t stream) {
    const float* features = (const float*)d_in[0];
    const int*   src      = (const int*)d_in[1];
    const int*   dst      = (const int*)d_in[2];
    const int N = in_sizes[0] / FEAT;
    const int E = in_sizes[1];

    // ---- carve workspace ----
    char* ws = (char*)d_ws;
    size_t off = 0;
    auto carve = [&](size_t bytes) -> void* {
        void* p = ws + off;
        off = (off + bytes + 255) & ~(size_t)255;
        return p;
    };
    int*    deg     = (int*)carve((size_t)N * 4);
    int*    offs    = (int*)carve((size_t)(N + 1) * 4);
    int*    cursor  = (int*)carve((size_t)N * 4);
    int*    bsums   = (int*)carve(4096);
    int*    csr_src = (int*)carve((size_t)E * 4);
    float*  el      = (float*)carve((size_t)N * NHEAD * 4);
    float*  er      = (float*)carve((size_t)N * NHEAD * 4);
    ushort* featB   = (ushort*)carve((size_t)N * FEAT * 2);
    ushort* inAh    = (ushort*)carve((size_t)N * FEAT * 2);
    ushort* inAl    = (ushort*)carve((size_t)N * FEAT * 2);
    ushort* Wh[3], *Wl[3];
    for (int i = 0; i < 3; ++i) {
        Wh[i] = (ushort*)carve((size_t)FEAT * FEAT * 2);
        Wl[i] = (ushort*)carve((size_t)FEAT * FEAT * 2);
    }

    const int nbE = (E + 255) / 256;
    const int nbN = (N + 255) / 256;

    // ---- CSR build + W prep ----
    hipMemsetAsync(deg, 0, (size_t)N * 4, stream);
    hist_kernel<<<nbE, 256, 0, stream>>>(dst, deg, E);
    scan_block<<<nbN, 256, 0, stream>>>(deg, offs, bsums, N);
    scan_sums<<<1, 256, 0, stream>>>(bsums, nbN);
    scan_add<<<nbN, 256, 0, stream>>>(offs, cursor, bsums, N, E);
    scatter_kernel<<<nbE, 256, 0, stream>>>(src, dst, cursor, csr_src, E);
    dim3 wgrid(FEAT, 3);
    wprep3_kernel<<<wgrid, FEAT, 0, stream>>>((const float*)d_in[3], (const float*)d_in[7],
                                              (const float*)d_in[11],
                                              Wh[0], Wl[0], Wh[1], Wl[1], Wh[2], Wl[2]);

    const int gemmBlocks = (N + GBM - 1) / GBM;
    const int nodeBlocks = (N + 3) / 4;

    // ---- layer 1 (f32 features, inline split) ----
    gemm_fused_f32a<<<gemmBlocks, 256, 0, stream>>>(features, Wh[0], Wl[0],
                                                    (const float*)d_in[4], (const float*)d_in[5],
                                                    featB, el, er, N);
    agg_kernel5<<<nodeBlocks, 256, 0, stream>>>(featB, el, er, offs, csr_src,
                                                (const float*)d_in[6],
                                                (float*)nullptr, inAh, inAl, 1, N);
    // ---- layer 2 ----
    gemm_fused<<<gemmBlocks, 256, 0, stream>>>(inAh, inAl, Wh[1], Wl[1],
                                               (const float*)d_in[8], (const float*)d_in[9],
                                               featB, el, er, N);
    agg_kernel5<<<nodeBlocks, 256, 0, stream>>>(featB, el, er, offs, csr_src,
                                                (const float*)d_in[10],
                                                (float*)nullptr, inAh, inAl, 1, N);
    // ---- layer 3 ----
    gemm_fused<<<gemmBlocks, 256, 0, stream>>>(inAh, inAl, Wh[2], Wl[2],
                                               (const float*)d_in[12], (const float*)d_in[13],
                                               featB, el, er, N);
    agg_kernel5<<<nodeBlocks, 256, 0, stream>>>(featB, el, er, offs, csr_src,
                                                (const float*)d_in[14],
                                                (float*)d_out, (ushort*)nullptr, (ushort*)nullptr, 0, N);
}

// Round 20
// 450.153 us; speedup vs baseline: 1.0644x; 1.0644x over previous
//
#include <hip/hip_runtime.h>
#include <hip/hip_bf16.h>
#include <cstdint>

// ---------------------------------------------------------------------------
// GAT 3-layer forward. N=50000, E=800000, H=4, D=64 (FEAT = H*D = 256 = F_IN).
// R20: revert agg to R18's rolled gather loop (R19's unrolled fast path doubled
//      VGPR 32->64, halved occupancy 68->37%, +15us/dispatch). Keep R19's GEMM
//      k-loop (loads after barrier + B reg-dbuf, measured -3.5us/dispatch).
// ---------------------------------------------------------------------------

#define FEAT 256
#define NHEAD 4

typedef short short8 __attribute__((ext_vector_type(8)));
typedef float f32x4 __attribute__((ext_vector_type(4)));

__device__ __forceinline__ ushort f2bf(float v) {
    uint u = __float_as_uint(v);
    uint r = (u + 0x7fffu + ((u >> 16) & 1u)) >> 16;
    return (ushort)r;
}
__device__ __forceinline__ float bf2f(ushort h) {
    return __uint_as_float(((uint)h) << 16);
}

// ---------------- CSR build ----------------
__global__ void hist_kernel(const int* __restrict__ dst, int* __restrict__ deg, int E) {
    int e = blockIdx.x * 256 + threadIdx.x;
    if (e < E) atomicAdd(&deg[dst[e]], 1);
}

__global__ void scan_block(const int* __restrict__ deg, int* __restrict__ offs,
                           int* __restrict__ bsums, int n) {
    __shared__ int s[256];
    int i = blockIdx.x * 256 + threadIdx.x;
    int v = (i < n) ? deg[i] : 0;
    s[threadIdx.x] = v; __syncthreads();
    #pragma unroll
    for (int off = 1; off < 256; off <<= 1) {
        int t = (threadIdx.x >= off) ? s[threadIdx.x - off] : 0;
        __syncthreads();
        s[threadIdx.x] += t;
        __syncthreads();
    }
    if (i < n) offs[i] = s[threadIdx.x] - v;
    if (threadIdx.x == 255) bsums[blockIdx.x] = s[255];
}

__global__ void scan_sums(int* __restrict__ bsums, int nb) {
    __shared__ int s[256];
    int v = (threadIdx.x < nb) ? bsums[threadIdx.x] : 0;
    s[threadIdx.x] = v; __syncthreads();
    #pragma unroll
    for (int off = 1; off < 256; off <<= 1) {
        int t = (threadIdx.x >= off) ? s[threadIdx.x - off] : 0;
        __syncthreads();
        s[threadIdx.x] += t;
        __syncthreads();
    }
    if (threadIdx.x < nb) bsums[threadIdx.x] = s[threadIdx.x] - v;
}

__global__ void scan_add(int* __restrict__ offs, int* __restrict__ cursor,
                         const int* __restrict__ bsums, int n, int total) {
    int i = blockIdx.x * 256 + threadIdx.x;
    if (i < n) {
        int o = offs[i] + bsums[i >> 8];
        offs[i] = o;
        cursor[i] = o;
    }
    if (i == 0) offs[n] = total;
}

__global__ void scatter_kernel(const int* __restrict__ src, const int* __restrict__ dst,
                               int* __restrict__ cursor, int* __restrict__ csr_src, int E) {
    int e = blockIdx.x * 256 + threadIdx.x;
    if (e < E) {
        int d = dst[e];
        int pos = atomicAdd(&cursor[d], 1);
        csr_src[pos] = src[e];
    }
}

// ---------------- W prep (all 3 layers in one dispatch) ----------------
__global__ void wprep3_kernel(const float* __restrict__ W0, const float* __restrict__ W1,
                              const float* __restrict__ W2,
                              ushort* __restrict__ Wh0, ushort* __restrict__ Wl0,
                              ushort* __restrict__ Wh1, ushort* __restrict__ Wl1,
                              ushort* __restrict__ Wh2, ushort* __restrict__ Wl2) {
    const float* W = (blockIdx.y == 0) ? W0 : (blockIdx.y == 1) ? W1 : W2;
    ushort* Wh = (blockIdx.y == 0) ? Wh0 : (blockIdx.y == 1) ? Wh1 : Wh2;
    ushort* Wl = (blockIdx.y == 0) ? Wl0 : (blockIdx.y == 1) ? Wl1 : Wl2;
    int n = blockIdx.x;
    int k = threadIdx.x;
    float v = W[(size_t)k * FEAT + n];
    ushort h = f2bf(v);
    float r = v - bf2f(h);
    Wh[(size_t)n * FEAT + k] = h;
    Wl[(size_t)n * FEAT + k] = f2bf(r);
}

// ---------------- fused GEMM 64x256 ----------------
#define GBM 64
#define GBK 32
#define LDK 40    // padded K stride in ushorts (80 B rows)
#define NKIT (FEAT / GBK)   // 8
#define TLD 264   // epilogue transpose row stride (ushorts)
#define SMEM_USHORTS 16896  // max(k-loop 10240, epilogue 64*264)

__device__ __forceinline__ void gemm_epilogue(ushort* smem, f32x4 (*acc)[4],
                                              const float* alv, const float* arv,
                                              ushort* featB, float* el, float* er,
                                              int row0, int wid, int lane, int tid, int M) {
    const int fr = lane & 15;
    const int q  = lane >> 4;
    float al4[4], ar4[4];
    #pragma unroll
    for (int nt = 0; nt < 4; ++nt) {
        al4[nt] = alv[wid * 64 + nt * 16 + fr];
        ar4[nt] = arv[wid * 64 + nt * 16 + fr];
    }
    #pragma unroll
    for (int mt = 0; mt < 4; ++mt) {
        #pragma unroll
        for (int r = 0; r < 4; ++r) {
            int row = row0 + mt * 16 + q * 4 + r;
            bool ok = row < M;
            float pl = 0.f, pr = 0.f;
            #pragma unroll
            for (int nt = 0; nt < 4; ++nt) {
                float v = acc[mt][nt][r];
                pl = fmaf(v, al4[nt], pl);
                pr = fmaf(v, ar4[nt], pr);
            }
            #pragma unroll
            for (int o = 1; o < 16; o <<= 1) {
                pl += __shfl_xor(pl, o, 64);
                pr += __shfl_xor(pr, o, 64);
            }
            if (ok && fr == 0) {
                el[(size_t)row * NHEAD + wid] = pl;
                er[(size_t)row * NHEAD + wid] = pr;
            }
        }
    }
    __syncthreads();
    ushort (*T)[TLD] = (ushort(*)[TLD])smem;
    #pragma unroll
    for (int mt = 0; mt < 4; ++mt) {
        #pragma unroll
        for (int nt = 0; nt < 4; ++nt) {
            #pragma unroll
            for (int r = 0; r < 4; ++r) {
                int row = mt * 16 + q * 4 + r;
                T[row][wid * 64 + nt * 16 + fr] = f2bf(acc[mt][nt][r]);
            }
        }
    }
    __syncthreads();
    #pragma unroll
    for (int j = 0; j < 8; ++j) {
        int p = j * 256 + tid;
        int row = p >> 5;
        int pc = p & 31;
        if (row0 + row < M) {
            short8 v = *(const short8*)&T[row][pc * 8];
            *(short8*)(featB + (size_t)(row0 + row) * FEAT + pc * 8) = v;
        }
    }
}

__global__ __launch_bounds__(256) void gemm_fused(const ushort* __restrict__ Ahg,
                                                  const ushort* __restrict__ Alg,
                                                  const ushort* __restrict__ Whg,
                                                  const ushort* __restrict__ Wlg,
                                                  const float* __restrict__ alv,
                                                  const float* __restrict__ arv,
                                                  ushort* __restrict__ featB,
                                                  float* __restrict__ el,
                                                  float* __restrict__ er, int M) {
    __shared__ ushort smem[SMEM_USHORTS];
    ushort (*Ah)[GBM][LDK] = (ushort(*)[GBM][LDK])smem;
    ushort (*Al)[GBM][LDK] = (ushort(*)[GBM][LDK])(smem + 2 * GBM * LDK);

    const int tid  = threadIdx.x;
    const int lane = tid & 63;
    const int wid  = tid >> 6;
    const int row0 = blockIdx.x * GBM;

    const int arow = tid >> 2;
    const int achk = (tid & 3) * 8;
    const bool aok = (row0 + arow) < M;
    const ushort* ApH = Ahg + (size_t)(row0 + arow) * FEAT + achk;
    const ushort* ApL = Alg + (size_t)(row0 + arow) * FEAT + achk;

    const int fr = lane & 15;
    const int fk = (lane >> 4) * 8;

    f32x4 acc[4][4];
    #pragma unroll
    for (int i = 0; i < 4; ++i)
        #pragma unroll
        for (int j = 0; j < 4; ++j) {
            f32x4 z = {0.f, 0.f, 0.f, 0.f};
            acc[i][j] = z;
        }

    const short8 z8 = {0, 0, 0, 0, 0, 0, 0, 0};
    short8 bfh[2][4], bfl[2][4];

    // prologue: stage A(0) into LDS[0]; load B(0) into reg buf 0
    {
        short8 a_h = aok ? *(const short8*)(ApH) : z8;
        short8 a_l = aok ? *(const short8*)(ApL) : z8;
        *(short8*)&Ah[0][arow][achk] = a_h;
        *(short8*)&Al[0][arow][achk] = a_l;
        #pragma unroll
        for (int nt = 0; nt < 4; ++nt) {
            size_t boff = (size_t)(wid * 64 + nt * 16 + fr) * FEAT + fk;
            bfh[0][nt] = *(const short8*)(Whg + boff);
            bfl[0][nt] = *(const short8*)(Wlg + boff);
        }
    }

    #pragma unroll
    for (int t = 0; t < NKIT; ++t) {
        const int cur = t & 1;
        const int k1 = (t + 1) * GBK;
        __syncthreads();   // A(t) LDS visible
        // issue next-iter loads AFTER the barrier so MFMA(t) hides their latency
        short8 a_h = z8, a_l = z8;
        if (t + 1 < NKIT) {
            if (aok) {
                a_h = *(const short8*)(ApH + k1);
                a_l = *(const short8*)(ApL + k1);
            }
            #pragma unroll
            for (int nt = 0; nt < 4; ++nt) {
                size_t boff = (size_t)(wid * 64 + nt * 16 + fr) * FEAT + k1 + fk;
                bfh[cur ^ 1][nt] = *(const short8*)(Whg + boff);
                bfl[cur ^ 1][nt] = *(const short8*)(Wlg + boff);
            }
        }
        #pragma unroll
        for (int mt = 0; mt < 4; ++mt) {
            short8 afh = *(const short8*)&Ah[cur][mt * 16 + fr][fk];
            short8 afl = *(const short8*)&Al[cur][mt * 16 + fr][fk];
            #pragma unroll
            for (int nt = 0; nt < 4; ++nt) {
                acc[mt][nt] = __builtin_amdgcn_mfma_f32_16x16x32_bf16(
                    afh, bfh[cur][nt], acc[mt][nt], 0, 0, 0);
                acc[mt][nt] = __builtin_amdgcn_mfma_f32_16x16x32_bf16(
                    afh, bfl[cur][nt], acc[mt][nt], 0, 0, 0);
                acc[mt][nt] = __builtin_amdgcn_mfma_f32_16x16x32_bf16(
                    afl, bfh[cur][nt], acc[mt][nt], 0, 0, 0);
            }
        }
        if (t + 1 < NKIT) {
            *(short8*)&Ah[cur ^ 1][arow][achk] = a_h;   // waits A loads (post-MFMA)
            *(short8*)&Al[cur ^ 1][arow][achk] = a_l;
        }
    }

    gemm_epilogue(smem, acc, alv, arv, featB, el, er, row0, wid, lane, tid, M);
}

// ---------------- layer-1 GEMM: f32 A input, hi/lo split inline at staging ------
__global__ __launch_bounds__(256) void gemm_fused_f32a(const float* __restrict__ Af,
                                                       const ushort* __restrict__ Whg,
                                                       const ushort* __restrict__ Wlg,
                                                       const float* __restrict__ alv,
                                                       const float* __restrict__ arv,
                                                       ushort* __restrict__ featB,
                                                       float* __restrict__ el,
                                                       float* __restrict__ er, int M) {
    __shared__ ushort smem[SMEM_USHORTS];
    ushort (*Ah)[GBM][LDK] = (ushort(*)[GBM][LDK])smem;
    ushort (*Al)[GBM][LDK] = (ushort(*)[GBM][LDK])(smem + 2 * GBM * LDK);

    const int tid  = threadIdx.x;
    const int lane = tid & 63;
    const int wid  = tid >> 6;
    const int row0 = blockIdx.x * GBM;

    const int arow = tid >> 2;
    const int achk = (tid & 3) * 8;
    const bool aok = (row0 + arow) < M;
    const float* Ap = Af + (size_t)(row0 + arow) * FEAT + achk;

    const int fr = lane & 15;
    const int fk = (lane >> 4) * 8;

    f32x4 acc[4][4];
    #pragma unroll
    for (int i = 0; i < 4; ++i)
        #pragma unroll
        for (int j = 0; j < 4; ++j) {
            f32x4 z = {0.f, 0.f, 0.f, 0.f};
            acc[i][j] = z;
        }

    const float4 z4 = make_float4(0.f, 0.f, 0.f, 0.f);
    short8 bfh[2][4], bfl[2][4];

    auto split_store = [&](int buf, float4 f0, float4 f1) {
        float v[8] = {f0.x, f0.y, f0.z, f0.w, f1.x, f1.y, f1.z, f1.w};
        ushort hi[8], lo[8];
        #pragma unroll
        for (int k = 0; k < 8; ++k) {
            hi[k] = f2bf(v[k]);
            lo[k] = f2bf(v[k] - bf2f(hi[k]));
        }
        *(short8*)&Ah[buf][arow][achk] = *(short8*)hi;
        *(short8*)&Al[buf][arow][achk] = *(short8*)lo;
    };

    // prologue
    {
        float4 f0 = aok ? *(const float4*)(Ap)     : z4;
        float4 f1 = aok ? *(const float4*)(Ap + 4) : z4;
        split_store(0, f0, f1);
        #pragma unroll
        for (int nt = 0; nt < 4; ++nt) {
            size_t boff = (size_t)(wid * 64 + nt * 16 + fr) * FEAT + fk;
            bfh[0][nt] = *(const short8*)(Whg + boff);
            bfl[0][nt] = *(const short8*)(Wlg + boff);
        }
    }

    #pragma unroll
    for (int t = 0; t < NKIT; ++t) {
        const int cur = t & 1;
        const int k1 = (t + 1) * GBK;
        __syncthreads();
        float4 f0 = z4, f1 = z4;
        if (t + 1 < NKIT) {
            if (aok) {
                f0 = *(const float4*)(Ap + k1);
                f1 = *(const float4*)(Ap + k1 + 4);
            }
            #pragma unroll
            for (int nt = 0; nt < 4; ++nt) {
                size_t boff = (size_t)(wid * 64 + nt * 16 + fr) * FEAT + k1 + fk;
                bfh[cur ^ 1][nt] = *(const short8*)(Whg + boff);
                bfl[cur ^ 1][nt] = *(const short8*)(Wlg + boff);
            }
        }
        #pragma unroll
        for (int mt = 0; mt < 4; ++mt) {
            short8 afh = *(const short8*)&Ah[cur][mt * 16 + fr][fk];
            short8 afl = *(const short8*)&Al[cur][mt * 16 + fr][fk];
            #pragma unroll
            for (int nt = 0; nt < 4; ++nt) {
                acc[mt][nt] = __builtin_amdgcn_mfma_f32_16x16x32_bf16(
                    afh, bfh[cur][nt], acc[mt][nt], 0, 0, 0);
                acc[mt][nt] = __builtin_amdgcn_mfma_f32_16x16x32_bf16(
                    afh, bfl[cur][nt], acc[mt][nt], 0, 0, 0);
                acc[mt][nt] = __builtin_amdgcn_mfma_f32_16x16x32_bf16(
                    afl, bfh[cur][nt], acc[mt][nt], 0, 0, 0);
            }
        }
        if (t + 1 < NKIT) split_store(cur ^ 1, f0, f1);
    }

    gemm_epilogue(smem, acc, alv, arv, featB, el, er, row0, wid, lane, tid, M);
}

// ---------------- online-softmax aggregate, 2 edges per 16B load (rolled) --------
// One wave per node. e-phase: lane = 16h + j16 computes e/w for head h, slot j16.
// Gather: parity par=lane>>5 handles edges j0=2i+par; lane covers 8 feats at
// fb=(lane&31)*8; acc head hh=(lane&31)>>3; w from e-phase lane hh*16+j0.
// Rolled loop keeps VGPR at 32 -> 68% occupancy (R19's unroll doubled VGPR).
__global__ __launch_bounds__(256) void agg_kernel5(const ushort* __restrict__ featB,
                                                   const float* __restrict__ el,
                                                   const float* __restrict__ er,
                                                   const int* __restrict__ offs,
                                                   const int* __restrict__ csr_src,
                                                   const float* __restrict__ bias,
                                                   float* __restrict__ outF,
                                                   ushort* __restrict__ outH,
                                                   ushort* __restrict__ outL,
                                                   int act, int n) {
    int node = blockIdx.x * 4 + (threadIdx.x >> 6);
    if (node >= n) return;
    int lane = threadIdx.x & 63;
    int h   = lane >> 4;
    int j16 = lane & 15;
    int l31 = lane & 31;
    int par = lane >> 5;
    int fb  = l31 * 8;
    int hh  = l31 >> 3;
    int start = offs[node];
    int deg = offs[node + 1] - start;
    float erh = er[node * NHEAD + h];

    float m = -1e30f, ssum = 0.f;
    float a0 = 0.f, a1 = 0.f, a2 = 0.f, a3 = 0.f;
    float a4 = 0.f, a5 = 0.f, a6 = 0.f, a7 = 0.f;
    int sidx = (j16 < deg) ? csr_src[start + j16] : 0;

    for (int p0 = 0; p0 < deg; p0 += 16) {
        int pn = p0 + 16 + j16;
        int sidx_nx = (pn < deg) ? csr_src[start + pn] : 0;
        float e = -1e30f;
        if (p0 + j16 < deg) {
            float t = el[sidx * NHEAD + h] + erh;
            e = (t > 0.f) ? t : 0.2f * t;
        }
        float cm = e;
        #pragma unroll
        for (int o = 1; o < 16; o <<= 1) cm = fmaxf(cm, __shfl_xor(cm, o, 64));
        float newm = fmaxf(m, cm);
        float sc = __expf(m - newm);
        m = newm;
        ssum *= sc;
        float w = __expf(e - m);
        ssum += w;
        float scA = __shfl(sc, hh * 16, 64);
        a0 *= scA; a1 *= scA; a2 *= scA; a3 *= scA;
        a4 *= scA; a5 *= scA; a6 *= scA; a7 *= scA;
        int cnt = min(16, deg - p0);
        int iters = (cnt + 1) >> 1;
        for (int i = 0; i < iters; ++i) {
            int j0 = 2 * i + par;
            int sj = __shfl(sidx, j0, 16);
            float wj = __shfl(w, hh * 16 + j0, 64);
            short8 v = *(const short8*)(featB + (size_t)sj * FEAT + fb);
            a0 = fmaf(wj, bf2f((ushort)v[0]), a0);
            a1 = fmaf(wj, bf2f((ushort)v[1]), a1);
            a2 = fmaf(wj, bf2f((ushort)v[2]), a2);
            a3 = fmaf(wj, bf2f((ushort)v[3]), a3);
            a4 = fmaf(wj, bf2f((ushort)v[4]), a4);
            a5 = fmaf(wj, bf2f((ushort)v[5]), a5);
            a6 = fmaf(wj, bf2f((ushort)v[6]), a6);
            a7 = fmaf(wj, bf2f((ushort)v[7]), a7);
        }
        sidx = sidx_nx;
    }
    a0 += __shfl_xor(a0, 32, 64);
    a1 += __shfl_xor(a1, 32, 64);
    a2 += __shfl_xor(a2, 32, 64);
    a3 += __shfl_xor(a3, 32, 64);
    a4 += __shfl_xor(a4, 32, 64);
    a5 += __shfl_xor(a5, 32, 64);
    a6 += __shfl_xor(a6, 32, 64);
    a7 += __shfl_xor(a7, 32, 64);

    float st = ssum;
    #pragma unroll
    for (int o = 1; o < 16; o <<= 1) st += __shfl_xor(st, o, 64);
    float stA = __shfl(st, hh * 16, 64);
    if (par == 0) {
        float inv = 1.f / fmaxf(stA, 1e-9f);
        float4 b0 = *(const float4*)(bias + fb);
        float4 b1 = *(const float4*)(bias + fb + 4);
        float o0 = fmaf(a0, inv, b0.x);
        float o1 = fmaf(a1, inv, b0.y);
        float o2 = fmaf(a2, inv, b0.z);
        float o3 = fmaf(a3, inv, b0.w);
        float o4 = fmaf(a4, inv, b1.x);
        float o5 = fmaf(a5, inv, b1.y);
        float o6 = fmaf(a6, inv, b1.z);
        float o7 = fmaf(a7, inv, b1.w);
        if (act) {
            o0 = (o0 > 0.f) ? o0 : expm1f(o0);
            o1 = (o1 > 0.f) ? o1 : expm1f(o1);
            o2 = (o2 > 0.f) ? o2 : expm1f(o2);
            o3 = (o3 > 0.f) ? o3 : expm1f(o3);
            o4 = (o4 > 0.f) ? o4 : expm1f(o4);
            o5 = (o5 > 0.f) ? o5 : expm1f(o5);
            o6 = (o6 > 0.f) ? o6 : expm1f(o6);
            o7 = (o7 > 0.f) ? o7 : expm1f(o7);
        }
        if (outF) {
            *((float4*)(outF + (size_t)node * FEAT + fb))     = make_float4(o0, o1, o2, o3);
            *((float4*)(outF + (size_t)node * FEAT + fb + 4)) = make_float4(o4, o5, o6, o7);
        } else {
            ushort hi[8], lo[8];
            float ov[8] = {o0, o1, o2, o3, o4, o5, o6, o7};
            #pragma unroll
            for (int k = 0; k < 8; ++k) {
                hi[k] = f2bf(ov[k]);
                lo[k] = f2bf(ov[k] - bf2f(hi[k]));
            }
            *(short8*)(outH + (size_t)node * FEAT + fb) = *(short8*)hi;
            *(short8*)(outL + (size_t)node * FEAT + fb) = *(short8*)lo;
        }
    }
}

// ---------------------------------------------------------------------------
extern "C" void kernel_launch(void* const* d_in, const int* in_sizes, int n_in,
                              void* d_out, int out_size, void* d_ws, size_t ws_size,
                              hipStream_t stream) {
    const float* features = (const float*)d_in[0];
    const int*   src      = (const int*)d_in[1];
    const int*   dst      = (const int*)d_in[2];
    const int N = in_sizes[0] / FEAT;
    const int E = in_sizes[1];

    // ---- carve workspace ----
    char* ws = (char*)d_ws;
    size_t off = 0;
    auto carve = [&](size_t bytes) -> void* {
        void* p = ws + off;
        off = (off + bytes + 255) & ~(size_t)255;
        return p;
    };
    int*    deg     = (int*)carve((size_t)N * 4);
    int*    offs    = (int*)carve((size_t)(N + 1) * 4);
    int*    cursor  = (int*)carve((size_t)N * 4);
    int*    bsums   = (int*)carve(4096);
    int*    csr_src = (int*)carve((size_t)E * 4);
    float*  el      = (float*)carve((size_t)N * NHEAD * 4);
    float*  er      = (float*)carve((size_t)N * NHEAD * 4);
    ushort* featB   = (ushort*)carve((size_t)N * FEAT * 2);
    ushort* inAh    = (ushort*)carve((size_t)N * FEAT * 2);
    ushort* inAl    = (ushort*)carve((size_t)N * FEAT * 2);
    ushort* Wh[3], *Wl[3];
    for (int i = 0; i < 3; ++i) {
        Wh[i] = (ushort*)carve((size_t)FEAT * FEAT * 2);
        Wl[i] = (ushort*)carve((size_t)FEAT * FEAT * 2);
    }

    const int nbE = (E + 255) / 256;
    const int nbN = (N + 255) / 256;

    // ---- CSR build + W prep ----
    hipMemsetAsync(deg, 0, (size_t)N * 4, stream);
    hist_kernel<<<nbE, 256, 0, stream>>>(dst, deg, E);
    scan_block<<<nbN, 256, 0, stream>>>(deg, offs, bsums, N);
    scan_sums<<<1, 256, 0, stream>>>(bsums, nbN);
    scan_add<<<nbN, 256, 0, stream>>>(offs, cursor, bsums, N, E);
    scatter_kernel<<<nbE, 256, 0, stream>>>(src, dst, cursor, csr_src, E);
    dim3 wgrid(FEAT, 3);
    wprep3_kernel<<<wgrid, FEAT, 0, stream>>>((const float*)d_in[3], (const float*)d_in[7],
                                              (const float*)d_in[11],
                                              Wh[0], Wl[0], Wh[1], Wl[1], Wh[2], Wl[2]);

    const int gemmBlocks = (N + GBM - 1) / GBM;
    const int nodeBlocks = (N + 3) / 4;

    // ---- layer 1 (f32 features, inline split) ----
    gemm_fused_f32a<<<gemmBlocks, 256, 0, stream>>>(features, Wh[0], Wl[0],
                                                    (const float*)d_in[4], (const float*)d_in[5],
                                                    featB, el, er, N);
    agg_kernel5<<<nodeBlocks, 256, 0, stream>>>(featB, el, er, offs, csr_src,
                                                (const float*)d_in[6],
                                                (float*)nullptr, inAh, inAl, 1, N);
    // ---- layer 2 ----
    gemm_fused<<<gemmBlocks, 256, 0, stream>>>(inAh, inAl, Wh[1], Wl[1],
                                               (const float*)d_in[8], (const float*)d_in[9],
                                               featB, el, er, N);
    agg_kernel5<<<nodeBlocks, 256, 0, stream>>>(featB, el, er, offs, csr_src,
                                                (const float*)d_in[10],
                                                (float*)nullptr, inAh, inAl, 1, N);
    // ---- layer 3 ----
    gemm_fused<<<gemmBlocks, 256, 0, stream>>>(inAh, inAl, Wh[2], Wl[2],
                                               (const float*)d_in[12], (const float*)d_in[13],
                                               featB, el, er, N);
    agg_kernel5<<<nodeBlocks, 256, 0, stream>>>(featB, el, er, offs, csr_src,
                                                (const float*)d_in[14],
                                                (float*)d_out, (ushort*)nullptr, (ushort*)nullptr, 0, N);
}

// Round 22
// 438.869 us; speedup vs baseline: 1.0918x; 1.0257x over previous
//
#include <hip/hip_runtime.h>
#include <hip/hip_bf16.h>
#include <cstdint>

// ---------------------------------------------------------------------------
// GAT 3-layer forward. N=50000, E=800000, H=4, D=64 (FEAT = H*D = 256 = F_IN).
// R21 = R18 verbatim (measured best, 443.4us): gemm loads-BEFORE-barrier
// (R19/R20 loads-after-barrier + B reg-dbuf isolated to +7us), coalesced LDS
// transpose epilogue, rolled agg_kernel5 (32 VGPR, 70% occupancy, 72us).
// ---------------------------------------------------------------------------

#define FEAT 256
#define NHEAD 4

typedef short short8 __attribute__((ext_vector_type(8)));
typedef float f32x4 __attribute__((ext_vector_type(4)));

__device__ __forceinline__ ushort f2bf(float v) {
    uint u = __float_as_uint(v);
    uint r = (u + 0x7fffu + ((u >> 16) & 1u)) >> 16;
    return (ushort)r;
}
__device__ __forceinline__ float bf2f(ushort h) {
    return __uint_as_float(((uint)h) << 16);
}

// ---------------- CSR build ----------------
__global__ void hist_kernel(const int* __restrict__ dst, int* __restrict__ deg, int E) {
    int e = blockIdx.x * 256 + threadIdx.x;
    if (e < E) atomicAdd(&deg[dst[e]], 1);
}

__global__ void scan_block(const int* __restrict__ deg, int* __restrict__ offs,
                           int* __restrict__ bsums, int n) {
    __shared__ int s[256];
    int i = blockIdx.x * 256 + threadIdx.x;
    int v = (i < n) ? deg[i] : 0;
    s[threadIdx.x] = v; __syncthreads();
    #pragma unroll
    for (int off = 1; off < 256; off <<= 1) {
        int t = (threadIdx.x >= off) ? s[threadIdx.x - off] : 0;
        __syncthreads();
        s[threadIdx.x] += t;
        __syncthreads();
    }
    if (i < n) offs[i] = s[threadIdx.x] - v;
    if (threadIdx.x == 255) bsums[blockIdx.x] = s[255];
}

__global__ void scan_sums(int* __restrict__ bsums, int nb) {
    __shared__ int s[256];
    int v = (threadIdx.x < nb) ? bsums[threadIdx.x] : 0;
    s[threadIdx.x] = v; __syncthreads();
    #pragma unroll
    for (int off = 1; off < 256; off <<= 1) {
        int t = (threadIdx.x >= off) ? s[threadIdx.x - off] : 0;
        __syncthreads();
        s[threadIdx.x] += t;
        __syncthreads();
    }
    if (threadIdx.x < nb) bsums[threadIdx.x] = s[threadIdx.x] - v;
}

__global__ void scan_add(int* __restrict__ offs, int* __restrict__ cursor,
                         const int* __restrict__ bsums, int n, int total) {
    int i = blockIdx.x * 256 + threadIdx.x;
    if (i < n) {
        int o = offs[i] + bsums[i >> 8];
        offs[i] = o;
        cursor[i] = o;
    }
    if (i == 0) offs[n] = total;
}

__global__ void scatter_kernel(const int* __restrict__ src, const int* __restrict__ dst,
                               int* __restrict__ cursor, int* __restrict__ csr_src, int E) {
    int e = blockIdx.x * 256 + threadIdx.x;
    if (e < E) {
        int d = dst[e];
        int pos = atomicAdd(&cursor[d], 1);
        csr_src[pos] = src[e];
    }
}

// ---------------- W prep (all 3 layers in one dispatch) ----------------
__global__ void wprep3_kernel(const float* __restrict__ W0, const float* __restrict__ W1,
                              const float* __restrict__ W2,
                              ushort* __restrict__ Wh0, ushort* __restrict__ Wl0,
                              ushort* __restrict__ Wh1, ushort* __restrict__ Wl1,
                              ushort* __restrict__ Wh2, ushort* __restrict__ Wl2) {
    const float* W = (blockIdx.y == 0) ? W0 : (blockIdx.y == 1) ? W1 : W2;
    ushort* Wh = (blockIdx.y == 0) ? Wh0 : (blockIdx.y == 1) ? Wh1 : Wh2;
    ushort* Wl = (blockIdx.y == 0) ? Wl0 : (blockIdx.y == 1) ? Wl1 : Wl2;
    int n = blockIdx.x;
    int k = threadIdx.x;
    float v = W[(size_t)k * FEAT + n];
    ushort h = f2bf(v);
    float r = v - bf2f(h);
    Wh[(size_t)n * FEAT + k] = h;
    Wl[(size_t)n * FEAT + k] = f2bf(r);
}

// ---------------- fused GEMM 64x256: A dbuf in LDS, B global->reg ----------------
#define GBM 64
#define GBK 32
#define LDK 40    // padded K stride in ushorts (80 B rows)
#define NKIT (FEAT / GBK)   // 8
#define TLD 264   // epilogue transpose row stride (ushorts): 528 B, 16B-aligned
#define SMEM_USHORTS 16896  // max(k-loop 10240, epilogue 64*264)

__device__ __forceinline__ void gemm_epilogue(ushort* smem, f32x4 (*acc)[4],
                                              const float* alv, const float* arv,
                                              ushort* featB, float* el, float* er,
                                              int row0, int wid, int lane, int tid, int M) {
    const int fr = lane & 15;
    const int q  = lane >> 4;
    float al4[4], ar4[4];
    #pragma unroll
    for (int nt = 0; nt < 4; ++nt) {
        al4[nt] = alv[wid * 64 + nt * 16 + fr];
        ar4[nt] = arv[wid * 64 + nt * 16 + fr];
    }
    #pragma unroll
    for (int mt = 0; mt < 4; ++mt) {
        #pragma unroll
        for (int r = 0; r < 4; ++r) {
            int row = row0 + mt * 16 + q * 4 + r;
            bool ok = row < M;
            float pl = 0.f, pr = 0.f;
            #pragma unroll
            for (int nt = 0; nt < 4; ++nt) {
                float v = acc[mt][nt][r];
                pl = fmaf(v, al4[nt], pl);
                pr = fmaf(v, ar4[nt], pr);
            }
            #pragma unroll
            for (int o = 1; o < 16; o <<= 1) {
                pl += __shfl_xor(pl, o, 64);
                pr += __shfl_xor(pr, o, 64);
            }
            if (ok && fr == 0) {
                el[(size_t)row * NHEAD + wid] = pl;
                er[(size_t)row * NHEAD + wid] = pr;
            }
        }
    }
    __syncthreads();
    ushort (*T)[TLD] = (ushort(*)[TLD])smem;
    #pragma unroll
    for (int mt = 0; mt < 4; ++mt) {
        #pragma unroll
        for (int nt = 0; nt < 4; ++nt) {
            #pragma unroll
            for (int r = 0; r < 4; ++r) {
                int row = mt * 16 + q * 4 + r;
                T[row][wid * 64 + nt * 16 + fr] = f2bf(acc[mt][nt][r]);
            }
        }
    }
    __syncthreads();
    #pragma unroll
    for (int j = 0; j < 8; ++j) {
        int p = j * 256 + tid;
        int row = p >> 5;
        int pc = p & 31;
        if (row0 + row < M) {
            short8 v = *(const short8*)&T[row][pc * 8];
            *(short8*)(featB + (size_t)(row0 + row) * FEAT + pc * 8) = v;
        }
    }
}

__global__ __launch_bounds__(256) void gemm_fused(const ushort* __restrict__ Ahg,
                                                  const ushort* __restrict__ Alg,
                                                  const ushort* __restrict__ Whg,
                                                  const ushort* __restrict__ Wlg,
                                                  const float* __restrict__ alv,
                                                  const float* __restrict__ arv,
                                                  ushort* __restrict__ featB,
                                                  float* __restrict__ el,
                                                  float* __restrict__ er, int M) {
    __shared__ ushort smem[SMEM_USHORTS];
    ushort (*Ah)[GBM][LDK] = (ushort(*)[GBM][LDK])smem;
    ushort (*Al)[GBM][LDK] = (ushort(*)[GBM][LDK])(smem + 2 * GBM * LDK);

    const int tid  = threadIdx.x;
    const int lane = tid & 63;
    const int wid  = tid >> 6;
    const int row0 = blockIdx.x * GBM;

    const int arow = tid >> 2;
    const int achk = (tid & 3) * 8;
    const bool aok = (row0 + arow) < M;
    const ushort* ApH = Ahg + (size_t)(row0 + arow) * FEAT + achk;
    const ushort* ApL = Alg + (size_t)(row0 + arow) * FEAT + achk;

    const int fr = lane & 15;
    const int fk = (lane >> 4) * 8;

    f32x4 acc[4][4];
    #pragma unroll
    for (int i = 0; i < 4; ++i)
        #pragma unroll
        for (int j = 0; j < 4; ++j) {
            f32x4 z = {0.f, 0.f, 0.f, 0.f};
            acc[i][j] = z;
        }

    const short8 z8 = {0, 0, 0, 0, 0, 0, 0, 0};

    {
        short8 a_h = aok ? *(const short8*)(ApH) : z8;
        short8 a_l = aok ? *(const short8*)(ApL) : z8;
        *(short8*)&Ah[0][arow][achk] = a_h;
        *(short8*)&Al[0][arow][achk] = a_l;
    }

    #pragma unroll
    for (int t = 0; t < NKIT; ++t) {
        const int cur = t & 1;
        const int k0 = t * GBK;
        short8 a_h = z8, a_l = z8;
        if (t + 1 < NKIT && aok) {
            a_h = *(const short8*)(ApH + k0 + GBK);
            a_l = *(const short8*)(ApL + k0 + GBK);
        }
        short8 bfh[4], bfl[4];
        #pragma unroll
        for (int nt = 0; nt < 4; ++nt) {
            size_t boff = (size_t)(wid * 64 + nt * 16 + fr) * FEAT + k0 + fk;
            bfh[nt] = *(const short8*)(Whg + boff);
            bfl[nt] = *(const short8*)(Wlg + boff);
        }

        __syncthreads();

        #pragma unroll
        for (int mt = 0; mt < 4; ++mt) {
            short8 afh = *(const short8*)&Ah[cur][mt * 16 + fr][fk];
            short8 afl = *(const short8*)&Al[cur][mt * 16 + fr][fk];
            #pragma unroll
            for (int nt = 0; nt < 4; ++nt) {
                acc[mt][nt] = __builtin_amdgcn_mfma_f32_16x16x32_bf16(
                    afh, bfh[nt], acc[mt][nt], 0, 0, 0);
                acc[mt][nt] = __builtin_amdgcn_mfma_f32_16x16x32_bf16(
                    afh, bfl[nt], acc[mt][nt], 0, 0, 0);
                acc[mt][nt] = __builtin_amdgcn_mfma_f32_16x16x32_bf16(
                    afl, bfh[nt], acc[mt][nt], 0, 0, 0);
            }
        }
        if (t + 1 < NKIT) {
            *(short8*)&Ah[cur ^ 1][arow][achk] = a_h;
            *(short8*)&Al[cur ^ 1][arow][achk] = a_l;
        }
    }

    gemm_epilogue(smem, acc, alv, arv, featB, el, er, row0, wid, lane, tid, M);
}

// ---------------- layer-1 GEMM: f32 A input, hi/lo split inline at staging ------
__global__ __launch_bounds__(256) void gemm_fused_f32a(const float* __restrict__ Af,
                                                       const ushort* __restrict__ Whg,
                                                       const ushort* __restrict__ Wlg,
                                                       const float* __restrict__ alv,
                                                       const float* __restrict__ arv,
                                                       ushort* __restrict__ featB,
                                                       float* __restrict__ el,
                                                       float* __restrict__ er, int M) {
    __shared__ ushort smem[SMEM_USHORTS];
    ushort (*Ah)[GBM][LDK] = (ushort(*)[GBM][LDK])smem;
    ushort (*Al)[GBM][LDK] = (ushort(*)[GBM][LDK])(smem + 2 * GBM * LDK);

    const int tid  = threadIdx.x;
    const int lane = tid & 63;
    const int wid  = tid >> 6;
    const int row0 = blockIdx.x * GBM;

    const int arow = tid >> 2;
    const int achk = (tid & 3) * 8;
    const bool aok = (row0 + arow) < M;
    const float* Ap = Af + (size_t)(row0 + arow) * FEAT + achk;

    const int fr = lane & 15;
    const int fk = (lane >> 4) * 8;

    f32x4 acc[4][4];
    #pragma unroll
    for (int i = 0; i < 4; ++i)
        #pragma unroll
        for (int j = 0; j < 4; ++j) {
            f32x4 z = {0.f, 0.f, 0.f, 0.f};
            acc[i][j] = z;
        }

    const float4 z4 = make_float4(0.f, 0.f, 0.f, 0.f);

    auto split_store = [&](int buf, float4 f0, float4 f1) {
        float v[8] = {f0.x, f0.y, f0.z, f0.w, f1.x, f1.y, f1.z, f1.w};
        ushort hi[8], lo[8];
        #pragma unroll
        for (int k = 0; k < 8; ++k) {
            hi[k] = f2bf(v[k]);
            lo[k] = f2bf(v[k] - bf2f(hi[k]));
        }
        *(short8*)&Ah[buf][arow][achk] = *(short8*)hi;
        *(short8*)&Al[buf][arow][achk] = *(short8*)lo;
    };

    {
        float4 f0 = aok ? *(const float4*)(Ap)     : z4;
        float4 f1 = aok ? *(const float4*)(Ap + 4) : z4;
        split_store(0, f0, f1);
    }

    #pragma unroll
    for (int t = 0; t < NKIT; ++t) {
        const int cur = t & 1;
        const int k0 = t * GBK;
        float4 f0 = z4, f1 = z4;
        if (t + 1 < NKIT && aok) {
            f0 = *(const float4*)(Ap + k0 + GBK);
            f1 = *(const float4*)(Ap + k0 + GBK + 4);
        }
        short8 bfh[4], bfl[4];
        #pragma unroll
        for (int nt = 0; nt < 4; ++nt) {
            size_t boff = (size_t)(wid * 64 + nt * 16 + fr) * FEAT + k0 + fk;
            bfh[nt] = *(const short8*)(Whg + boff);
            bfl[nt] = *(const short8*)(Wlg + boff);
        }

        __syncthreads();

        #pragma unroll
        for (int mt = 0; mt < 4; ++mt) {
            short8 afh = *(const short8*)&Ah[cur][mt * 16 + fr][fk];
            short8 afl = *(const short8*)&Al[cur][mt * 16 + fr][fk];
            #pragma unroll
            for (int nt = 0; nt < 4; ++nt) {
                acc[mt][nt] = __builtin_amdgcn_mfma_f32_16x16x32_bf16(
                    afh, bfh[nt], acc[mt][nt], 0, 0, 0);
                acc[mt][nt] = __builtin_amdgcn_mfma_f32_16x16x32_bf16(
                    afh, bfl[nt], acc[mt][nt], 0, 0, 0);
                acc[mt][nt] = __builtin_amdgcn_mfma_f32_16x16x32_bf16(
                    afl, bfh[nt], acc[mt][nt], 0, 0, 0);
            }
        }
        if (t + 1 < NKIT) split_store(cur ^ 1, f0, f1);
    }

    gemm_epilogue(smem, acc, alv, arv, featB, el, er, row0, wid, lane, tid, M);
}

// ---------------- online-softmax aggregate, 2 edges per 16B load (rolled) --------
__global__ __launch_bounds__(256) void agg_kernel5(const ushort* __restrict__ featB,
                                                   const float* __restrict__ el,
                                                   const float* __restrict__ er,
                                                   const int* __restrict__ offs,
                                                   const int* __restrict__ csr_src,
                                                   const float* __restrict__ bias,
                                                   float* __restrict__ outF,
                                                   ushort* __restrict__ outH,
                                                   ushort* __restrict__ outL,
                                                   int act, int n) {
    int node = blockIdx.x * 4 + (threadIdx.x >> 6);
    if (node >= n) return;
    int lane = threadIdx.x & 63;
    int h   = lane >> 4;
    int j16 = lane & 15;
    int l31 = lane & 31;
    int par = lane >> 5;
    int fb  = l31 * 8;
    int hh  = l31 >> 3;
    int start = offs[node];
    int deg = offs[node + 1] - start;
    float erh = er[node * NHEAD + h];

    float m = -1e30f, ssum = 0.f;
    float a0 = 0.f, a1 = 0.f, a2 = 0.f, a3 = 0.f;
    float a4 = 0.f, a5 = 0.f, a6 = 0.f, a7 = 0.f;
    int sidx = (j16 < deg) ? csr_src[start + j16] : 0;

    for (int p0 = 0; p0 < deg; p0 += 16) {
        int pn = p0 + 16 + j16;
        int sidx_nx = (pn < deg) ? csr_src[start + pn] : 0;
        float e = -1e30f;
        if (p0 + j16 < deg) {
            float t = el[sidx * NHEAD + h] + erh;
            e = (t > 0.f) ? t : 0.2f * t;
        }
        float cm = e;
        #pragma unroll
        for (int o = 1; o < 16; o <<= 1) cm = fmaxf(cm, __shfl_xor(cm, o, 64));
        float newm = fmaxf(m, cm);
        float sc = __expf(m - newm);
        m = newm;
        ssum *= sc;
        float w = __expf(e - m);
        ssum += w;
        float scA = __shfl(sc, hh * 16, 64);
        a0 *= scA; a1 *= scA; a2 *= scA; a3 *= scA;
        a4 *= scA; a5 *= scA; a6 *= scA; a7 *= scA;
        int cnt = min(16, deg - p0);
        int iters = (cnt + 1) >> 1;
        for (int i = 0; i < iters; ++i) {
            int j0 = 2 * i + par;
            int sj = __shfl(sidx, j0, 16);
            float wj = __shfl(w, hh * 16 + j0, 64);
            short8 v = *(const short8*)(featB + (size_t)sj * FEAT + fb);
            a0 = fmaf(wj, bf2f((ushort)v[0]), a0);
            a1 = fmaf(wj, bf2f((ushort)v[1]), a1);
            a2 = fmaf(wj, bf2f((ushort)v[2]), a2);
            a3 = fmaf(wj, bf2f((ushort)v[3]), a3);
            a4 = fmaf(wj, bf2f((ushort)v[4]), a4);
            a5 = fmaf(wj, bf2f((ushort)v[5]), a5);
            a6 = fmaf(wj, bf2f((ushort)v[6]), a6);
            a7 = fmaf(wj, bf2f((ushort)v[7]), a7);
        }
        sidx = sidx_nx;
    }
    a0 += __shfl_xor(a0, 32, 64);
    a1 += __shfl_xor(a1, 32, 64);
    a2 += __shfl_xor(a2, 32, 64);
    a3 += __shfl_xor(a3, 32, 64);
    a4 += __shfl_xor(a4, 32, 64);
    a5 += __shfl_xor(a5, 32, 64);
    a6 += __shfl_xor(a6, 32, 64);
    a7 += __shfl_xor(a7, 32, 64);

    float st = ssum;
    #pragma unroll
    for (int o = 1; o < 16; o <<= 1) st += __shfl_xor(st, o, 64);
    float stA = __shfl(st, hh * 16, 64);
    if (par == 0) {
        float inv = 1.f / fmaxf(stA, 1e-9f);
        float4 b0 = *(const float4*)(bias + fb);
        float4 b1 = *(const float4*)(bias + fb + 4);
        float o0 = fmaf(a0, inv, b0.x);
        float o1 = fmaf(a1, inv, b0.y);
        float o2 = fmaf(a2, inv, b0.z);
        float o3 = fmaf(a3, inv, b0.w);
        float o4 = fmaf(a4, inv, b1.x);
        float o5 = fmaf(a5, inv, b1.y);
        float o6 = fmaf(a6, inv, b1.z);
        float o7 = fmaf(a7, inv, b1.w);
        if (act) {
            o0 = (o0 > 0.f) ? o0 : expm1f(o0);
            o1 = (o1 > 0.f) ? o1 : expm1f(o1);
            o2 = (o2 > 0.f) ? o2 : expm1f(o2);
            o3 = (o3 > 0.f) ? o3 : expm1f(o3);
            o4 = (o4 > 0.f) ? o4 : expm1f(o4);
            o5 = (o5 > 0.f) ? o5 : expm1f(o5);
            o6 = (o6 > 0.f) ? o6 : expm1f(o6);
            o7 = (o7 > 0.f) ? o7 : expm1f(o7);
        }
        if (outF) {
            *((float4*)(outF + (size_t)node * FEAT + fb))     = make_float4(o0, o1, o2, o3);
            *((float4*)(outF + (size_t)node * FEAT + fb + 4)) = make_float4(o4, o5, o6, o7);
        } else {
            ushort hi[8], lo[8];
            float ov[8] = {o0, o1, o2, o3, o4, o5, o6, o7};
            #pragma unroll
            for (int k = 0; k < 8; ++k) {
                hi[k] = f2bf(ov[k]);
                lo[k] = f2bf(ov[k] - bf2f(hi[k]));
            }
            *(short8*)(outH + (size_t)node * FEAT + fb) = *(short8*)hi;
            *(short8*)(outL + (size_t)node * FEAT + fb) = *(short8*)lo;
        }
    }
}

// ---------------------------------------------------------------------------
extern "C" void kernel_launch(void* const* d_in, const int* in_sizes, int n_in,
                              void* d_out, int out_size, void* d_ws, size_t ws_size,
                              hipStream_t stream) {
    const float* features = (const float*)d_in[0];
    const int*   src      = (const int*)d_in[1];
    const int*   dst      = (const int*)d_in[2];
    const int N = in_sizes[0] / FEAT;
    const int E = in_sizes[1];

    // ---- carve workspace ----
    char* ws = (char*)d_ws;
    size_t off = 0;
    auto carve = [&](size_t bytes) -> void* {
        void* p = ws + off;
        off = (off + bytes + 255) & ~(size_t)255;
        return p;
    };
    int*    deg     = (int*)carve((size_t)N * 4);
    int*    offs    = (int*)carve((size_t)(N + 1) * 4);
    int*    cursor  = (int*)carve((size_t)N * 4);
    int*    bsums   = (int*)carve(4096);
    int*    csr_src = (int*)carve((size_t)E * 4);
    float*  el      = (float*)carve((size_t)N * NHEAD * 4);
    float*  er      = (float*)carve((size_t)N * NHEAD * 4);
    ushort* featB   = (ushort*)carve((size_t)N * FEAT * 2);
    ushort* inAh    = (ushort*)carve((size_t)N * FEAT * 2);
    ushort* inAl    = (ushort*)carve((size_t)N * FEAT * 2);
    ushort* Wh[3], *Wl[3];
    for (int i = 0; i < 3; ++i) {
        Wh[i] = (ushort*)carve((size_t)FEAT * FEAT * 2);
        Wl[i] = (ushort*)carve((size_t)FEAT * FEAT * 2);
    }

    const int nbE = (E + 255) / 256;
    const int nbN = (N + 255) / 256;

    // ---- CSR build + W prep ----
    hipMemsetAsync(deg, 0, (size_t)N * 4, stream);
    hist_kernel<<<nbE, 256, 0, stream>>>(dst, deg, E);
    scan_block<<<nbN, 256, 0, stream>>>(deg, offs, bsums, N);
    scan_sums<<<1, 256, 0, stream>>>(bsums, nbN);
    scan_add<<<nbN, 256, 0, stream>>>(offs, cursor, bsums, N, E);
    scatter_kernel<<<nbE, 256, 0, stream>>>(src, dst, cursor, csr_src, E);
    dim3 wgrid(FEAT, 3);
    wprep3_kernel<<<wgrid, FEAT, 0, stream>>>((const float*)d_in[3], (const float*)d_in[7],
                                              (const float*)d_in[11],
                                              Wh[0], Wl[0], Wh[1], Wl[1], Wh[2], Wl[2]);

    const int gemmBlocks = (N + GBM - 1) / GBM;
    const int nodeBlocks = (N + 3) / 4;

    // ---- layer 1 (f32 features, inline split) ----
    gemm_fused_f32a<<<gemmBlocks, 256, 0, stream>>>(features, Wh[0], Wl[0],
                                                    (const float*)d_in[4], (const float*)d_in[5],
                                                    featB, el, er, N);
    agg_kernel5<<<nodeBlocks, 256, 0, stream>>>(featB, el, er, offs, csr_src,
                                                (const float*)d_in[6],
                                                (float*)nullptr, inAh, inAl, 1, N);
    // ---- layer 2 ----
    gemm_fused<<<gemmBlocks, 256, 0, stream>>>(inAh, inAl, Wh[1], Wl[1],
                                               (const float*)d_in[8], (const float*)d_in[9],
                                               featB, el, er, N);
    agg_kernel5<<<nodeBlocks, 256, 0, stream>>>(featB, el, er, offs, csr_src,
                                                (const float*)d_in[10],
                                                (float*)nullptr, inAh, inAl, 1, N);
    // ---- layer 3 ----
    gemm_fused<<<gemmBlocks, 256, 0, stream>>>(inAh, inAl, Wh[2], Wl[2],
                                               (const float*)d_in[12], (const float*)d_in[13],
                                               featB, el, er, N);
    agg_kernel5<<<nodeBlocks, 256, 0, stream>>>(featB, el, er, offs, csr_src,
                                                (const float*)d_in[14],
                                                (float*)d_out, (ushort*)nullptr, (ushort*)nullptr, 0, N);
}